// Round 6
// baseline (47.487 us; speedup 1.0000x reference)
//
#include <hip/hip_runtime.h>

#define BATCH 262144
#define NUM_LAYERS 64
#define WINDOWS 4
#define WIN_LAYERS (NUM_LAYERS / WINDOWS)   // 16

typedef float f32x4 __attribute__((ext_vector_type(4)));

// U(phi,theta,omega) = Rz(omega) * Ry(theta) * Rz(phi).
// Propagate the pre-omega state u_l = Rz(-omega_l) * t_l:
//   u_l = Ry(theta_l) * Rz(phi_l + omega_{l-1}) * u_{l-1}
// omega is batch-independent; sincos(omega/2) precomputed per layer; the
// store-side Rz(omega) costs 4 fma (real part only in MODE 0).
//
// Layer-windowed recompute: block handles (batch-chunk, window w). It runs
// layers [0, 16w) updating state only (no stores, no inter-block deps), then
// layers [16w, 16w+16) with stores. 4x more resident waves supplying stores.
// Each thread handles TWO batch elements -> one float4 store per layer.
template <int MODE>
__global__ __launch_bounds__(256) void squbit_kernel(
    const float* __restrict__ X,       // (BATCH, 2)
    const float* __restrict__ W,       // (NUM_LAYERS, 3)
    const float* __restrict__ Bi,      // (NUM_LAYERS, 3)
    float* __restrict__ out)
{
    __shared__ float4 cA[NUM_LAYERS];   // {0.5*w0, 0.5*b0 + hom_prev, 0.5*w1, 0.5*b1}
    __shared__ float2 cOm[NUM_LAYERS];  // {cos(om/2), sin(om/2)}

    const int t = threadIdx.x;
    if (t < NUM_LAYERS) {
        const float w0 = W[t * 3 + 0], w1 = W[t * 3 + 1], w2 = W[t * 3 + 2];
        const float b0 = Bi[t * 3 + 0], b1 = Bi[t * 3 + 1], b2 = Bi[t * 3 + 2];
        float hom_prev = 0.0f;
        if (t > 0) hom_prev = 0.5f * (W[(t - 1) * 3 + 2] + Bi[(t - 1) * 3 + 2]);
        cA[t] = make_float4(0.5f * w0, fmaf(0.5f, b0, hom_prev), 0.5f * w1, 0.5f * b1);
        const float hom = 0.5f * (w2 + b2);
        float so, co;
        __sincosf(hom, &so, &co);
        cOm[t] = make_float2(co, so);
    }
    __syncthreads();

    const int w  = blockIdx.x & (WINDOWS - 1);        // layer window
    const int g  = (blockIdx.x >> 2) * 256 + t;       // batch pair index: elems 2g, 2g+1
    const int l0 = w * WIN_LAYERS;

    const float4 xx = reinterpret_cast<const float4*>(X)[g];

    // pre-omega states u = (u0, u1), init (1,0)
    float Aur0 = 1.0f, Aui0 = 0.0f, Aur1 = 0.0f, Aui1 = 0.0f;
    float Bur0 = 1.0f, Bui0 = 0.0f, Bur1 = 0.0f, Bui1 = 0.0f;

    f32x4* o4 = reinterpret_cast<f32x4*>(out);

    // ---- prefix: state recurrence only ----
    #pragma unroll 4
    for (int l = 0; l < l0; ++l) {
        const float4 c = cA[l];
        {
            const float hpsi = fmaf(xx.x, c.x, c.y);
            const float hth  = fmaf(xx.y, c.z, c.w);
            float sps, cps, sth, cth;
            __sincosf(hpsi, &sps, &cps);
            __sincosf(hth,  &sth, &cth);
            const float a0r = fmaf(Aui0,  sps, Aur0 * cps);
            const float a0i = fmaf(Aur0, -sps, Aui0 * cps);
            const float a1r = fmaf(Aui1, -sps, Aur1 * cps);
            const float a1i = fmaf(Aur1,  sps, Aui1 * cps);
            Aur0 = fmaf(-sth, a1r, cth * a0r);
            Aui0 = fmaf(-sth, a1i, cth * a0i);
            Aur1 = fmaf( sth, a0r, cth * a1r);
            Aui1 = fmaf( sth, a0i, cth * a1i);
        }
        {
            const float hpsi = fmaf(xx.z, c.x, c.y);
            const float hth  = fmaf(xx.w, c.z, c.w);
            float sps, cps, sth, cth;
            __sincosf(hpsi, &sps, &cps);
            __sincosf(hth,  &sth, &cth);
            const float a0r = fmaf(Bui0,  sps, Bur0 * cps);
            const float a0i = fmaf(Bur0, -sps, Bui0 * cps);
            const float a1r = fmaf(Bui1, -sps, Bur1 * cps);
            const float a1i = fmaf(Bur1,  sps, Bui1 * cps);
            Bur0 = fmaf(-sth, a1r, cth * a0r);
            Bui0 = fmaf(-sth, a1i, cth * a0i);
            Bur1 = fmaf( sth, a0r, cth * a1r);
            Bui1 = fmaf( sth, a0i, cth * a1i);
        }
    }

    // ---- window: state recurrence + stores ----
    #pragma unroll 4
    for (int l = l0; l < l0 + WIN_LAYERS; ++l) {
        const float4 c = cA[l];
        const float2 om = cOm[l];
        {
            const float hpsi = fmaf(xx.x, c.x, c.y);
            const float hth  = fmaf(xx.y, c.z, c.w);
            float sps, cps, sth, cth;
            __sincosf(hpsi, &sps, &cps);
            __sincosf(hth,  &sth, &cth);
            const float a0r = fmaf(Aui0,  sps, Aur0 * cps);
            const float a0i = fmaf(Aur0, -sps, Aui0 * cps);
            const float a1r = fmaf(Aui1, -sps, Aur1 * cps);
            const float a1i = fmaf(Aur1,  sps, Aui1 * cps);
            Aur0 = fmaf(-sth, a1r, cth * a0r);
            Aui0 = fmaf(-sth, a1i, cth * a0i);
            Aur1 = fmaf( sth, a0r, cth * a1r);
            Aui1 = fmaf( sth, a0i, cth * a1i);
        }
        {
            const float hpsi = fmaf(xx.z, c.x, c.y);
            const float hth  = fmaf(xx.w, c.z, c.w);
            float sps, cps, sth, cth;
            __sincosf(hpsi, &sps, &cps);
            __sincosf(hth,  &sth, &cth);
            const float a0r = fmaf(Bui0,  sps, Bur0 * cps);
            const float a0i = fmaf(Bur0, -sps, Bui0 * cps);
            const float a1r = fmaf(Bui1, -sps, Bur1 * cps);
            const float a1i = fmaf(Bur1,  sps, Bui1 * cps);
            Bur0 = fmaf(-sth, a1r, cth * a0r);
            Bui0 = fmaf(-sth, a1i, cth * a0i);
            Bur1 = fmaf( sth, a0r, cth * a1r);
            Bui1 = fmaf( sth, a0i, cth * a1i);
        }

        if (MODE == 0) {
            const float At0r = fmaf(Aui0,  om.y, Aur0 * om.x);
            const float At1r = fmaf(Aui1, -om.y, Aur1 * om.x);
            const float Bt0r = fmaf(Bui0,  om.y, Bur0 * om.x);
            const float Bt1r = fmaf(Bui1, -om.y, Bur1 * om.x);
            f32x4 v; v.x = At0r; v.y = At1r; v.z = Bt0r; v.w = Bt1r;
            o4[l * (BATCH / 2) + g] = v;
        } else {
            const float At0r = fmaf(Aui0,  om.y, Aur0 * om.x);
            const float At0i = fmaf(Aur0, -om.y, Aui0 * om.x);
            const float At1r = fmaf(Aui1, -om.y, Aur1 * om.x);
            const float At1i = fmaf(Aur1,  om.y, Aui1 * om.x);
            const float Bt0r = fmaf(Bui0,  om.y, Bur0 * om.x);
            const float Bt0i = fmaf(Bur0, -om.y, Bui0 * om.x);
            const float Bt1r = fmaf(Bui1, -om.y, Bur1 * om.x);
            const float Bt1i = fmaf(Bur1,  om.y, Bui1 * om.x);
            f32x4 va; va.x = At0r; va.y = At0i; va.z = At1r; va.w = At1i;
            f32x4 vb; vb.x = Bt0r; vb.y = Bt0i; vb.z = Bt1r; vb.w = Bt1i;
            o4[(l * BATCH + 2 * g) + 0] = va;
            o4[(l * BATCH + 2 * g) + 1] = vb;
        }
    }
}

extern "C" void kernel_launch(void* const* d_in, const int* in_sizes, int n_in,
                              void* d_out, int out_size, void* d_ws, size_t ws_size,
                              hipStream_t stream) {
    const float* X  = (const float*)d_in[0];
    const float* W  = (const float*)d_in[1];
    const float* Bi = (const float*)d_in[2];
    float* out = (float*)d_out;

    dim3 grid((BATCH / 512) * WINDOWS), block(256);   // 2048 blocks = 8/CU

    const long long full_complex_floats = (long long)NUM_LAYERS * BATCH * 4;
    if ((long long)out_size >= full_complex_floats) {
        squbit_kernel<1><<<grid, block, 0, stream>>>(X, W, Bi, out);
    } else {
        squbit_kernel<0><<<grid, block, 0, stream>>>(X, W, Bi, out);
    }
}

// Round 7
// 26.804 us; speedup vs baseline: 1.7716x; 1.7716x over previous
//
#include <hip/hip_runtime.h>

#define BATCH 262144
#define NUM_LAYERS 64

typedef float f32x2 __attribute__((ext_vector_type(2)));
typedef float f32x4 __attribute__((ext_vector_type(4)));

// U(phi,theta,omega) = Rz(omega) * Ry(theta) * Rz(phi).
// Propagate pre-omega state u_l = Rz(-omega_l)*t_l:
//   u_l = Ry(theta_l) * Rz(phi_l + omega_{l-1}) * u_{l-1}
// omega batch-independent -> sincos(omega/2) per layer precomputed; store-side
// Rz(omega) is 4 packed ops (real part only in MODE 0).
// Two batch elements per thread, carried in the TWO LANES of packed-f32
// vectors (v_pk_fma_f32 path, full-rate FP32x2 on gfx950): lane.x = elem A,
// lane.y = elem B. Only the 4 sincos per layer are scalar.
template <int MODE>
__global__ __launch_bounds__(256) void squbit_kernel(
    const float* __restrict__ X,       // (BATCH, 2)
    const float* __restrict__ W,       // (NUM_LAYERS, 3)
    const float* __restrict__ Bi,      // (NUM_LAYERS, 3)
    float* __restrict__ out)
{
    __shared__ float4 cA[NUM_LAYERS];   // {0.5*w0, 0.5*b0 + hom_prev, 0.5*w1, 0.5*b1}
    __shared__ float2 cOm[NUM_LAYERS];  // {cos(om/2), sin(om/2)}

    const int t = threadIdx.x;
    if (t < NUM_LAYERS) {
        const float w0 = W[t * 3 + 0], w1 = W[t * 3 + 1], w2 = W[t * 3 + 2];
        const float b0 = Bi[t * 3 + 0], b1 = Bi[t * 3 + 1], b2 = Bi[t * 3 + 2];
        float hom_prev = 0.0f;
        if (t > 0) hom_prev = 0.5f * (W[(t - 1) * 3 + 2] + Bi[(t - 1) * 3 + 2]);
        cA[t] = make_float4(0.5f * w0, fmaf(0.5f, b0, hom_prev), 0.5f * w1, 0.5f * b1);
        const float hom = 0.5f * (w2 + b2);
        float so, co;
        __sincosf(hom, &so, &co);
        cOm[t] = make_float2(co, so);
    }
    __syncthreads();

    const int g = blockIdx.x * 256 + t;          // batch elems 2g (A), 2g+1 (B)
    const float4 xx = reinterpret_cast<const float4*>(X)[g];

    const f32x2 x0 = {xx.x, xx.z};   // X[:,0] for A,B
    const f32x2 x1 = {xx.y, xx.w};   // X[:,1] for A,B

    // pre-omega state, lanes = (A,B): amplitudes u0 = ur0 + i*ui0, u1 = ur1 + i*ui1
    f32x2 ur0 = {1.0f, 1.0f}, ui0 = {0.0f, 0.0f};
    f32x2 ur1 = {0.0f, 0.0f}, ui1 = {0.0f, 0.0f};

    f32x4* o4 = reinterpret_cast<f32x4*>(out);

    #pragma unroll 4
    for (int l = 0; l < NUM_LAYERS; ++l) {
        const float4 c = cA[l];
        const float2 om = cOm[l];

        const f32x2 hpsi = x0 * c.x + c.y;   // v_pk_fma
        const f32x2 hth  = x1 * c.z + c.w;

        float sps0, cps0, sps1, cps1, sth0, cth0, sth1, cth1;
        __sincosf(hpsi.x, &sps0, &cps0);
        __sincosf(hpsi.y, &sps1, &cps1);
        __sincosf(hth.x,  &sth0, &cth0);
        __sincosf(hth.y,  &sth1, &cth1);
        const f32x2 sps = {sps0, sps1}, cps = {cps0, cps1};
        const f32x2 sth = {sth0, sth1}, cth = {cth0, cth1};

        // Rz(psi): a0 = u0 * (cps - i*sps); a1 = u1 * (cps + i*sps)   [packed]
        const f32x2 a0r = ui0 * sps + ur0 * cps;
        const f32x2 a0i = ui0 * cps - ur0 * sps;
        const f32x2 a1r = ur1 * cps - ui1 * sps;
        const f32x2 a1i = ui1 * cps + ur1 * sps;
        // Ry(th)                                                      [packed]
        ur0 = cth * a0r - sth * a1r;
        ui0 = cth * a0i - sth * a1i;
        ur1 = sth * a0r + cth * a1r;
        ui1 = sth * a0i + cth * a1i;

        // store-side Rz(omega): t0 = u0*(co - i so), t1 = u1*(co + i so)
        if (MODE == 0) {
            const f32x2 t0r = ui0 * om.y + ur0 * om.x;
            const f32x2 t1r = ur1 * om.x - ui1 * om.y;
            f32x4 v; v.x = t0r.x; v.y = t1r.x; v.z = t0r.y; v.w = t1r.y;
            o4[l * (BATCH / 2) + g] = v;
        } else {
            const f32x2 t0r = ui0 * om.y + ur0 * om.x;
            const f32x2 t0i = ui0 * om.x - ur0 * om.y;
            const f32x2 t1r = ur1 * om.x - ui1 * om.y;
            const f32x2 t1i = ui1 * om.x + ur1 * om.y;
            f32x4 va; va.x = t0r.x; va.y = t0i.x; va.z = t1r.x; va.w = t1i.x;
            f32x4 vb; vb.x = t0r.y; vb.y = t0i.y; vb.z = t1r.y; vb.w = t1i.y;
            o4[(l * BATCH + 2 * g) + 0] = va;
            o4[(l * BATCH + 2 * g) + 1] = vb;
        }
    }
}

extern "C" void kernel_launch(void* const* d_in, const int* in_sizes, int n_in,
                              void* d_out, int out_size, void* d_ws, size_t ws_size,
                              hipStream_t stream) {
    const float* X  = (const float*)d_in[0];
    const float* W  = (const float*)d_in[1];
    const float* Bi = (const float*)d_in[2];
    float* out = (float*)d_out;

    dim3 grid(BATCH / 512), block(256);   // 2 batch elems per thread

    const long long full_complex_floats = (long long)NUM_LAYERS * BATCH * 4;
    if ((long long)out_size >= full_complex_floats) {
        squbit_kernel<1><<<grid, block, 0, stream>>>(X, W, Bi, out);
    } else {
        squbit_kernel<0><<<grid, block, 0, stream>>>(X, W, Bi, out);
    }
}